// Round 1
// baseline (370.135 us; speedup 1.0000x reference)
//
#include <hip/hip_runtime.h>
#include <cstdint>
#include <cstddef>
#include <utility>

#define SS 512
#define TT 32
#define NB 256
#define KSTEPS 510  // SS-2

// ---------- unroll helper (compile-time indices -> registers, swizzle imms) ----------
template <typename F, size_t... Is>
__device__ __forceinline__ void unroll_impl(F&& f, std::index_sequence<Is...>) {
  (f(std::integral_constant<int, (int)Is>{}), ...);
}
template <int N, typename F>
__device__ __forceinline__ void unrollN(F&& f) {
  unroll_impl(f, std::make_index_sequence<N>{});
}

// broadcast lane I within each 32-lane group (BitMode: and=0, or=I, xor=0)
template <int I>
__device__ __forceinline__ float bcast32(float v) {
  return __int_as_float(__builtin_amdgcn_ds_swizzle(__float_as_int(v), (I << 5)));
}
// butterfly xor D within each 32-lane group (and=0x1f, xor=D)
template <int D>
__device__ __forceinline__ float bfly32(float v) {
  return __int_as_float(__builtin_amdgcn_ds_swizzle(__float_as_int(v), (D << 10) | 0x1f));
}
template <int D>
__device__ __forceinline__ int bfly32i(int v) {
  return __builtin_amdgcn_ds_swizzle(v, (D << 10) | 0x1f);
}

// ---------- mask dtype autodetect (bool may arrive as i32 / u8 / f32) ----------
__device__ __forceinline__ int mask_mode(const void* m) {
  int w0 = ((const int*)m)[0];          // element (0,0) is always true (L>=256)
  if (w0 == 1) return 0;                // int32 0/1
  if (w0 == 0x3f800000) return 2;       // float32 1.0
  return 1;                             // uint8 (0x01010101) or anything else
}
__device__ __forceinline__ bool mask_at(const void* m, int idx, int mode) {
  if (mode == 0) return ((const int*)m)[idx] != 0;
  if (mode == 2) return ((const float*)m)[idx] != 0.0f;
  return ((const unsigned char*)m)[idx] != 0;
}

__device__ __forceinline__ int seq_length(const void* mask, int b, int tid, int mode) {
  int cnt = 0;
  for (int s = tid; s < SS; s += 64) cnt += mask_at(mask, b * SS + s, mode) ? 1 : 0;
  for (int d = 1; d < 64; d <<= 1) cnt += __shfl_xor(cnt, d, 64);
  return cnt;  // all lanes hold total
}

// ---------- K1: fused forward / viterbi / gold (role by blockIdx) ----------
__global__ __launch_bounds__(64) void crf_main_kernel(
    const float* __restrict__ feats, const float* __restrict__ trans,
    const void* __restrict__ mask, const int* __restrict__ tags,
    unsigned char* __restrict__ ws_bp, float* __restrict__ ws_fwd,
    float* __restrict__ ws_gold, int* __restrict__ ws_ptr) {
  const int blk = blockIdx.x;
  const int tid = threadIdx.x;
  const int mode = mask_mode(mask);

  if (blk < NB) {
    // ================= FORWARD (log-space via exp trick) =================
    const int b = blk;
    const int j = tid & 31;
    const int L = seq_length(mask, b, tid, mode);
    const int steps = L - 2;
    const float* fb = feats + (size_t)b * (SS * TT);

    float E[TT];
    unrollN<TT>([&](auto I) { constexpr int i = I; E[i] = __expf(trans[i * TT + j]); });

    float p = fb[1 * TT + j];
    float fcur = fb[2 * TT + j];
    for (int k = 0; k < steps; ++k) {
      int nrow = (k + 3 < SS) ? (k + 3) : (SS - 1);
      float fnext = fb[nrow * TT + j];  // prefetch (clamped, avoids OOB)
      // m = max over 32 lanes of p
      float m = p;
      unrollN<5>([&](auto D) { constexpr int d = 1 << D; m = fmaxf(m, bfly32<d>(m)); });
      float a = __expf(p - m);
      float P = 0.0f;
      unrollN<TT>([&](auto I) { constexpr int i = I; P = fmaf(bcast32<i>(a), E[i], P); });
      p = fcur + m + __logf(P);
      fcur = fnext;
    }
    // forward score: logsumexp over lanes
    float m = p;
    unrollN<5>([&](auto D) { constexpr int d = 1 << D; m = fmaxf(m, bfly32<d>(m)); });
    float sacc = __expf(p - m);
    unrollN<5>([&](auto D) { constexpr int d = 1 << D; sacc += bfly32<d>(sacc); });
    if (tid == 0) ws_fwd[b] = m + __logf(sacc);

  } else if (blk < 2 * NB) {
    // ================= VITERBI (bit-exact vs reference) =================
    const int b = blk - NB;
    const int j = tid & 31;
    const int L = seq_length(mask, b, tid, mode);
    const int steps = L - 2;
    const float* fb = feats + (size_t)b * (SS * TT);
    unsigned char* bpb = ws_bp + (size_t)b * (KSTEPS * TT);

    float C[TT];
    unrollN<TT>([&](auto I) { constexpr int i = I; C[i] = trans[i * TT + j]; });

    float p = fb[1 * TT + j];
    float fcur = fb[2 * TT + j];
    for (int k = 0; k < steps; ++k) {
      int nrow = (k + 3 < SS) ? (k + 3) : (SS - 1);
      float fnext = fb[nrow * TT + j];
      float best = -3.402823466e38f;
      int bidx = 0;
      unrollN<TT>([&](auto I) {
        constexpr int i = I;
        float d = fcur + C[i];            // fl(f + trans)  (reference op order)
        float v = bcast32<i>(p) + d;      // fl(part + fl(f+trans))
        bool c = v > best;                // strict > keeps FIRST max (jnp.argmax)
        best = c ? v : best;
        bidx = c ? i : bidx;
      });
      if (tid < 32) bpb[k * TT + j] = (unsigned char)bidx;
      p = best;
      fcur = fnext;
    }
    // pointer = argmax_j of partition entering step L-2 (first-max tiebreak)
    float v = p;
    int idx = j;
    unrollN<5>([&](auto D) {
      constexpr int d = 1 << D;
      float vo = bfly32<d>(v);
      int io = bfly32i<d>(idx);
      bool take = (vo > v) || ((vo == v) && (io < idx));
      v = take ? vo : v;
      idx = take ? io : idx;
    });
    if (tid == 0) ws_ptr[b] = idx;
    // zero bp rows k in [steps, 510): reference masks bps to 0 there
    int* bpw = (int*)bpb;  // row base is 16320*b, 4-aligned
    for (int w = steps * 8 + tid; w < KSTEPS * 8; w += 64) bpw[w] = 0;

  } else {
    // ================= GOLD SCORE =================
    const int b = blk - 2 * NB;
    float acc = 0.0f;
    for (int s = tid; s < SS; s += 64) {
      if (s == 0) continue;
      if (!mask_at(mask, b * SS + s, mode)) continue;
      int tg = tags[b * SS + s];
      if (tg == -100) tg = 0;
      float e = feats[((size_t)b * SS + s) * TT + tg];
      if (s >= 2) {
        int tp = tags[b * SS + s - 1];
        if (tp == -100) tp = 0;
        e += trans[tp * TT + tg];
      }
      acc += e;
    }
    for (int d = 1; d < 64; d <<= 1) acc += __shfl_xor(acc, d, 64);
    if (tid == 0) ws_gold[b] = acc;
  }
}

// ---------- K2: chunk-parallel backtrace ----------
__global__ __launch_bounds__(512) void crf_backtrace_kernel(
    const unsigned char* __restrict__ ws_bp, const int* __restrict__ ws_ptr,
    float* __restrict__ out_decode) {
  __shared__ unsigned char bp[KSTEPS * TT];     // 16320 B
  __shared__ unsigned char path[KSTEPS * TT];   // 16320 B
  __shared__ int entries[8];

  const int b = blockIdx.x;
  const int tid = threadIdx.x;

  // stage bp to LDS
  const int* src = (const int*)(ws_bp + (size_t)b * (KSTEPS * TT));
  int* dst = (int*)bp;
  for (int w = tid; w < KSTEPS * 8; w += 512) dst[w] = src[w];
  __syncthreads();

  // each wave = one 64-step chunk; lanes 0..31 = entry-tag hypotheses
  const int wave = tid >> 6;
  const int lane = tid & 63;
  if (lane < 32) {
    const int lo = wave * 64;
    const int hi = (lo + 64 < KSTEPS) ? (lo + 64) : KSTEPS;
    int ptr = lane;
    for (int k = hi - 1; k >= lo; --k) {
      ptr = bp[k * TT + ptr];
      path[k * TT + lane] = (unsigned char)ptr;
    }
  }
  __syncthreads();

  // compose chunk entries from the top (chunk 7 enters with pointer)
  if (tid == 0) {
    int e = ws_ptr[b];
    for (int c = 7; c >= 0; --c) {
      entries[c] = e;
      e = path[(c * 64) * TT + e];  // exit of chunk c = entry of chunk c-1
    }
  }
  __syncthreads();

  // decode row: [0, ptrs[0..509], pointer]
  const int s = tid;
  int val;
  if (s == 0) val = 0;
  else if (s <= KSTEPS) { int k = s - 1; val = path[k * TT + entries[k >> 6]]; }
  else val = ws_ptr[b];
  out_decode[(size_t)b * SS + s] = (float)val;
}

// ---------- K3: loss + path_score ----------
__global__ __launch_bounds__(256) void crf_finish_kernel(
    const float* __restrict__ ws_fwd, const float* __restrict__ ws_gold,
    float* __restrict__ out) {
  const int tid = threadIdx.x;
  out[1 + tid] = 0.0f;  // path_score = zeros(B)
  if (tid < 64) {
    float sf = 0.0f, sg = 0.0f;
    for (int r = 0; r < 4; ++r) {
      sf += ws_fwd[tid + 64 * r];
      sg += ws_gold[tid + 64 * r];
    }
    for (int d = 1; d < 64; d <<= 1) {
      sf += __shfl_xor(sf, d, 64);
      sg += __shfl_xor(sg, d, 64);
    }
    if (tid == 0) out[0] = (sf - sg) / 256.0f;
  }
}

extern "C" void kernel_launch(void* const* d_in, const int* in_sizes, int n_in,
                              void* d_out, int out_size, void* d_ws, size_t ws_size,
                              hipStream_t stream) {
  const float* feats = (const float*)d_in[0];
  const float* trans = (const float*)d_in[1];
  const void* mask = d_in[2];
  const int* tags = (const int*)d_in[3];
  float* out = (float*)d_out;

  unsigned char* ws = (unsigned char*)d_ws;
  const size_t BP_BYTES = (size_t)NB * KSTEPS * TT;  // 4,177,920
  unsigned char* ws_bp = ws;
  float* ws_fwd = (float*)(ws + BP_BYTES);
  float* ws_gold = (float*)(ws + BP_BYTES + 1024);
  int* ws_ptr = (int*)(ws + BP_BYTES + 2048);

  hipLaunchKernelGGL(crf_main_kernel, dim3(3 * NB), dim3(64), 0, stream,
                     feats, trans, mask, tags, ws_bp, ws_fwd, ws_gold, ws_ptr);
  hipLaunchKernelGGL(crf_backtrace_kernel, dim3(NB), dim3(512), 0, stream,
                     ws_bp, ws_ptr, out + 1 + NB);
  hipLaunchKernelGGL(crf_finish_kernel, dim3(1), dim3(256), 0, stream,
                     ws_fwd, ws_gold, out);
}

// Round 2
// 223.173 us; speedup vs baseline: 1.6585x; 1.6585x over previous
//
#include <hip/hip_runtime.h>
#include <cstdint>
#include <cstddef>
#include <utility>

#define SS 512
#define TT 32
#define NB 256
#define KSTEPS 510  // SS-2

// ---------- unroll helper (compile-time indices -> registers, swizzle imms) ----------
template <typename F, size_t... Is>
__device__ __forceinline__ void unroll_impl(F&& f, std::index_sequence<Is...>) {
  (f(std::integral_constant<int, (int)Is>{}), ...);
}
template <int N, typename F>
__device__ __forceinline__ void unrollN(F&& f) {
  unroll_impl(f, std::make_index_sequence<N>{});
}

// broadcast lane I within each 32-lane group (BitMode: and=0, or=I, xor=0)
template <int I>
__device__ __forceinline__ float bcast32(float v) {
  return __int_as_float(__builtin_amdgcn_ds_swizzle(__float_as_int(v), (I << 5)));
}
// butterfly xor D within each 32-lane group (and=0x1f, xor=D)
template <int D>
__device__ __forceinline__ float bfly32(float v) {
  return __int_as_float(__builtin_amdgcn_ds_swizzle(__float_as_int(v), (D << 10) | 0x1f));
}
template <int D>
__device__ __forceinline__ int bfly32i(int v) {
  return __builtin_amdgcn_ds_swizzle(v, (D << 10) | 0x1f);
}

// ---------- mask dtype autodetect (bool may arrive as i32 / u8 / f32) ----------
__device__ __forceinline__ int mask_mode(const void* m) {
  int w0 = ((const int*)m)[0];          // element (0,0) is always true (L>=256)
  if (w0 == 1) return 0;                // int32 0/1
  if (w0 == 0x3f800000) return 2;       // float32 1.0
  return 1;                             // uint8
}
__device__ __forceinline__ bool mask_at(const void* m, int idx, int mode) {
  if (mode == 0) return ((const int*)m)[idx] != 0;
  if (mode == 2) return ((const float*)m)[idx] != 0.0f;
  return ((const unsigned char*)m)[idx] != 0;
}

__device__ __forceinline__ int seq_length(const void* mask, int b, int tid, int mode) {
  int cnt = 0;
  for (int s = tid; s < SS; s += 64) cnt += mask_at(mask, b * SS + s, mode) ? 1 : 0;
  for (int d = 1; d < 64; d <<= 1) cnt += __shfl_xor(cnt, d, 64);
  return cnt;
}

// ---------- K1: fused forward / viterbi / gold (role by blockIdx) ----------
// Lane layout: lane l owns tag j = (l&31) ^ ((l&32)>>1). Half h = l>>5 covers
// source-tag range i in [16h, 16h+16). A single bcast32<ii> then delivers
// p[ii] to half 0 and p[16+ii] to half 1 (because half 1's lane ii owns tag
// 16+ii). Halves combine via shfl_xor lane^48 (= partner owning same tag).
__global__ __launch_bounds__(64) void crf_main_kernel(
    const float* __restrict__ feats, const float* __restrict__ trans,
    const void* __restrict__ mask, const int* __restrict__ tags,
    unsigned char* __restrict__ ws_bp, float* __restrict__ ws_fwd,
    float* __restrict__ ws_gold, int* __restrict__ ws_ptr) {
  const int blk = blockIdx.x;
  const int tid = threadIdx.x;
  const int mode = mask_mode(mask);

  const int h = tid >> 5;                       // half
  const int j = (tid & 31) ^ (h << 4);          // owned tag (permuted in half 1)

  if (blk < NB) {
    // ================= FORWARD (exp-trick, readfirstlane shift) =================
    const int b = blk;
    const int L = seq_length(mask, b, tid, mode);
    const int steps = L - 2;
    const float* fb = feats + (size_t)b * (SS * TT);

    float E[16];  // rows 16h..16h+15 of exp(trans), column j
    unrollN<16>([&](auto I) {
      constexpr int ii = I;
      E[ii] = __expf(trans[(h * 16 + ii) * TT + j]);
    });

    float p = fb[1 * TT + j];
    float fcur = fb[2 * TT + j];
    for (int k = 0; k < steps; ++k) {
      int nrow = (k + 3 < SS) ? (k + 3) : (SS - 1);
      float fnext = fb[nrow * TT + j];
      float m = __int_as_float(__builtin_amdgcn_readfirstlane(__float_as_int(p)));
      float a = __expf(p - m);
      float P0 = 0.f, P1 = 0.f, P2 = 0.f, P3 = 0.f;
      unrollN<16>([&](auto I) {
        constexpr int ii = I;
        float bc = bcast32<ii>(a);          // a[16h+ii] in this half
        if constexpr ((ii & 3) == 0) P0 = fmaf(bc, E[ii], P0);
        else if constexpr ((ii & 3) == 1) P1 = fmaf(bc, E[ii], P1);
        else if constexpr ((ii & 3) == 2) P2 = fmaf(bc, E[ii], P2);
        else P3 = fmaf(bc, E[ii], P3);
      });
      float P = (P0 + P1) + (P2 + P3);
      float Pt = P + __shfl_xor(P, 48, 64);   // combine i-halves (same tag)
      p = fcur + (m + __logf(Pt));
      fcur = fnext;
    }
    // forward score: logsumexp over the 32 tags (each 32-group holds all tags)
    float m = p;
    unrollN<5>([&](auto D) { constexpr int d = 1 << D; m = fmaxf(m, bfly32<d>(m)); });
    float sacc = __expf(p - m);
    unrollN<5>([&](auto D) { constexpr int d = 1 << D; sacc += bfly32<d>(sacc); });
    if (tid == 0) ws_fwd[b] = m + __logf(sacc);

  } else if (blk < 2 * NB) {
    // ================= VITERBI (bit-exact vs reference) =================
    const int b = blk - NB;
    const int L = seq_length(mask, b, tid, mode);
    const int steps = L - 2;
    const float* fb = feats + (size_t)b * (SS * TT);
    unsigned char* bpb = ws_bp + (size_t)b * (KSTEPS * TT);

    float C[16];  // rows 16h..16h+15 of trans, column j
    unrollN<16>([&](auto I) {
      constexpr int ii = I;
      C[ii] = trans[(h * 16 + ii) * TT + j];
    });

    float p = fb[1 * TT + j];
    float fcur = fb[2 * TT + j];
    for (int k = 0; k < steps; ++k) {
      int nrow = (k + 3 < SS) ? (k + 3) : (SS - 1);
      float fnext = fb[nrow * TT + j];
      float cur[16];
      unrollN<16>([&](auto I) {
        constexpr int ii = I;
        float d = fcur + C[ii];             // fl(f + trans)  (reference order)
        cur[ii] = bcast32<ii>(p) + d;       // fl(fl(f+trans) + part)
      });
      // exact max via tree (associative)
      float t8[8], t4[4], t2[2];
      unrollN<8>([&](auto Q) { constexpr int q = Q; t8[q] = fmaxf(cur[2 * q], cur[2 * q + 1]); });
      unrollN<4>([&](auto Q) { constexpr int q = Q; t4[q] = fmaxf(t8[2 * q], t8[2 * q + 1]); });
      t2[0] = fmaxf(t4[0], t4[1]); t2[1] = fmaxf(t4[2], t4[3]);
      float vmax = fmaxf(t2[0], t2[1]);
      // first-max index within this half (descending overwrite-on-equal)
      int bi = 0;
      unrollN<16>([&](auto I) { constexpr int ii = 15 - I; bi = (cur[ii] == vmax) ? ii : bi; });
      int gi = bi | (h << 4);               // global source tag
      // cross-half combine (partner lane^48 owns same target tag, other i-range)
      float vo = __shfl_xor(vmax, 48, 64);
      int go = __shfl_xor(gi, 48, 64);
      bool take = (vo > vmax) || ((vo == vmax) && (go < gi));
      float pn = take ? vo : vmax;
      int bidx = take ? go : gi;
      if (tid < 32) bpb[k * TT + tid] = (unsigned char)bidx;  // lane l<32 owns tag l
      p = pn;
      fcur = fnext;
    }
    // pointer = first-max argmax over tags of p
    float v = p;
    int idx = j;
    unrollN<5>([&](auto D) {
      constexpr int d = 1 << D;
      float vo = bfly32<d>(v);
      int io = bfly32i<d>(idx);
      bool take = (vo > v) || ((vo == v) && (io < idx));
      v = take ? vo : v;
      idx = take ? io : idx;
    });
    if (tid == 0) ws_ptr[b] = idx;
    // zero bp rows k in [steps, 510): reference masks bps to 0 there
    int* bpw = (int*)bpb;
    for (int w = steps * 8 + tid; w < KSTEPS * 8; w += 64) bpw[w] = 0;

  } else {
    // ================= GOLD SCORE =================
    const int b = blk - 2 * NB;
    float acc = 0.0f;
    for (int s = tid; s < SS; s += 64) {
      if (s == 0) continue;
      if (!mask_at(mask, b * SS + s, mode)) continue;
      int tg = tags[b * SS + s];
      if (tg == -100) tg = 0;
      float e = feats[((size_t)b * SS + s) * TT + tg];
      if (s >= 2) {
        int tp = tags[b * SS + s - 1];
        if (tp == -100) tp = 0;
        e += trans[tp * TT + tg];
      }
      acc += e;
    }
    for (int d = 1; d < 64; d <<= 1) acc += __shfl_xor(acc, d, 64);
    if (tid == 0) ws_gold[b] = acc;
  }
}

// ---------- K2: chunk-parallel backtrace + loss/path_score finish ----------
__global__ __launch_bounds__(512) void crf_backtrace_kernel(
    const unsigned char* __restrict__ ws_bp, const int* __restrict__ ws_ptr,
    const float* __restrict__ ws_fwd, const float* __restrict__ ws_gold,
    float* __restrict__ out) {
  __shared__ unsigned char bp[KSTEPS * TT];     // 16320 B
  __shared__ unsigned char path[KSTEPS * TT];   // 16320 B
  __shared__ int entries[8];

  const int b = blockIdx.x;
  const int tid = threadIdx.x;
  float* out_decode = out + 1 + NB;

  if (tid == 0) out[1 + b] = 0.0f;  // path_score = zeros(B)
  if (b == 0 && tid >= 64 && tid < 128) {
    // loss = (sum(fwd) - sum(gold)) / B   (one wave, independent of decode work)
    int t = tid - 64;
    float sf = 0.0f, sg = 0.0f;
    for (int r = 0; r < 4; ++r) { sf += ws_fwd[t + 64 * r]; sg += ws_gold[t + 64 * r]; }
    for (int d = 1; d < 64; d <<= 1) { sf += __shfl_xor(sf, d, 64); sg += __shfl_xor(sg, d, 64); }
    if (t == 0) out[0] = (sf - sg) / 256.0f;
  }

  // stage bp to LDS
  const int* src = (const int*)(ws_bp + (size_t)b * (KSTEPS * TT));
  int* dst = (int*)bp;
  for (int w = tid; w < KSTEPS * 8; w += 512) dst[w] = src[w];
  __syncthreads();

  // each wave = one 64-step chunk; lanes 0..31 = entry-tag hypotheses
  const int wave = tid >> 6;
  const int lane = tid & 63;
  if (lane < 32) {
    const int lo = wave * 64;
    const int hi = (lo + 64 < KSTEPS) ? (lo + 64) : KSTEPS;
    int ptr = lane;
    for (int k = hi - 1; k >= lo; --k) {
      ptr = bp[k * TT + ptr];
      path[k * TT + lane] = (unsigned char)ptr;
    }
  }
  __syncthreads();

  // compose chunk entries from the top (chunk 7 enters with pointer)
  if (tid == 0) {
    int e = ws_ptr[b];
    for (int c = 7; c >= 0; --c) {
      entries[c] = e;
      e = path[(c * 64) * TT + e];
    }
  }
  __syncthreads();

  // decode row: [0, ptrs[0..509], pointer]
  const int s = tid;
  int val;
  if (s == 0) val = 0;
  else if (s <= KSTEPS) { int k = s - 1; val = path[k * TT + entries[k >> 6]]; }
  else val = ws_ptr[b];
  out_decode[(size_t)b * SS + s] = (float)val;
}

extern "C" void kernel_launch(void* const* d_in, const int* in_sizes, int n_in,
                              void* d_out, int out_size, void* d_ws, size_t ws_size,
                              hipStream_t stream) {
  const float* feats = (const float*)d_in[0];
  const float* trans = (const float*)d_in[1];
  const void* mask = d_in[2];
  const int* tags = (const int*)d_in[3];
  float* out = (float*)d_out;

  unsigned char* ws = (unsigned char*)d_ws;
  const size_t BP_BYTES = (size_t)NB * KSTEPS * TT;  // 4,177,920
  unsigned char* ws_bp = ws;
  float* ws_fwd = (float*)(ws + BP_BYTES);
  float* ws_gold = (float*)(ws + BP_BYTES + 1024);
  int* ws_ptr = (int*)(ws + BP_BYTES + 2048);

  hipLaunchKernelGGL(crf_main_kernel, dim3(3 * NB), dim3(64), 0, stream,
                     feats, trans, mask, tags, ws_bp, ws_fwd, ws_gold, ws_ptr);
  hipLaunchKernelGGL(crf_backtrace_kernel, dim3(NB), dim3(512), 0, stream,
                     ws_bp, ws_ptr, ws_fwd, ws_gold, out);
}

// Round 3
// 179.131 us; speedup vs baseline: 2.0663x; 1.2459x over previous
//
#include <hip/hip_runtime.h>
#include <cstdint>
#include <cstddef>
#include <utility>

#define SS 512
#define TT 32
#define NB 256
#define KSTEPS 510  // SS-2

// ---------- unroll helper (compile-time indices -> registers, swizzle imms) ----------
template <typename F, size_t... Is>
__device__ __forceinline__ void unroll_impl(F&& f, std::index_sequence<Is...>) {
  (f(std::integral_constant<int, (int)Is>{}), ...);
}
template <int N, typename F>
__device__ __forceinline__ void unrollN(F&& f) {
  unroll_impl(f, std::make_index_sequence<N>{});
}

// broadcast lane I within each 32-lane group (BitMode: and=0, or=I, xor=0)
template <int I>
__device__ __forceinline__ float bcast32(float v) {
  return __int_as_float(__builtin_amdgcn_ds_swizzle(__float_as_int(v), (I << 5)));
}
// butterfly xor D within each 32-lane group (and=0x1f, xor=D)
template <int D>
__device__ __forceinline__ float bfly32(float v) {
  return __int_as_float(__builtin_amdgcn_ds_swizzle(__float_as_int(v), (D << 10) | 0x1f));
}
template <int D>
__device__ __forceinline__ int bfly32i(int v) {
  return __builtin_amdgcn_ds_swizzle(v, (D << 10) | 0x1f);
}

// ---------- mask dtype autodetect (bool may arrive as i32 / u8 / f32) ----------
__device__ __forceinline__ int mask_mode(const void* m) {
  int w0 = ((const int*)m)[0];          // element (0,0) is always true (L>=256)
  if (w0 == 1) return 0;                // int32 0/1
  if (w0 == 0x3f800000) return 2;       // float32 1.0
  return 1;                             // uint8
}
__device__ __forceinline__ bool mask_at(const void* m, int idx, int mode) {
  if (mode == 0) return ((const int*)m)[idx] != 0;
  if (mode == 2) return ((const float*)m)[idx] != 0.0f;
  return ((const unsigned char*)m)[idx] != 0;
}

__device__ __forceinline__ int seq_length(const void* mask, int b, int tid, int mode) {
  int cnt = 0;
  for (int s = tid; s < SS; s += 64) cnt += mask_at(mask, b * SS + s, mode) ? 1 : 0;
  for (int d = 1; d < 64; d <<= 1) cnt += __shfl_xor(cnt, d, 64);
  return cnt;
}

// ---------- K1: fused forward / viterbi / gold (role by blockIdx) ----------
// Lane layout: lane l owns tag j = (l&31) ^ ((l&32)>>1). Half h = l>>5 covers
// source-tag range i in [16h, 16h+16). A single bcast32<ii> delivers p[16h+ii]
// to each half's lanes. Halves combine via shfl_xor lane^48 (partner owning
// the same target tag, other source-half).
// Deep prefetch: scan unrolled x8; all 8 next-row loads issue before the 8
// recurrence steps, so ~1200 cyc of compute hides the vmem latency.
__global__ __launch_bounds__(64) void crf_main_kernel(
    const float* __restrict__ feats, const float* __restrict__ trans,
    const void* __restrict__ mask, const int* __restrict__ tags,
    unsigned char* __restrict__ ws_bp, float* __restrict__ ws_fwd,
    float* __restrict__ ws_gold, int* __restrict__ ws_ptr) {
  const int blk = blockIdx.x;
  const int tid = threadIdx.x;
  const int mode = mask_mode(mask);

  const int h = tid >> 5;                       // half
  const int j = (tid & 31) ^ (h << 4);          // owned tag (permuted in half 1)

  if (blk < NB) {
    // ================= FORWARD (exp-trick, readfirstlane shift) =================
    const int b = blk;
    const int L = seq_length(mask, b, tid, mode);
    const int steps = L - 2;
    const float* fb = feats + (size_t)b * (SS * TT);

    float E[16];  // rows 16h..16h+15 of exp(trans), column j
    unrollN<16>([&](auto I) {
      constexpr int ii = I;
      E[ii] = __expf(trans[(h * 16 + ii) * TT + j]);
    });

    float p = fb[1 * TT + j];

    auto fwd_step = [&](float fcur) {
      float m = __int_as_float(__builtin_amdgcn_readfirstlane(__float_as_int(p)));
      float a = __expf(p - m);
      float P0 = 0.f, P1 = 0.f, P2 = 0.f, P3 = 0.f;
      unrollN<16>([&](auto I) {
        constexpr int ii = I;
        float bc = bcast32<ii>(a);          // a[16h+ii] in this half
        if constexpr ((ii & 3) == 0) P0 = fmaf(bc, E[ii], P0);
        else if constexpr ((ii & 3) == 1) P1 = fmaf(bc, E[ii], P1);
        else if constexpr ((ii & 3) == 2) P2 = fmaf(bc, E[ii], P2);
        else P3 = fmaf(bc, E[ii], P3);
      });
      float P = (P0 + P1) + (P2 + P3);
      float Pt = P + __shfl_xor(P, 48, 64);   // combine i-halves (same tag)
      p = fcur + (m + __logf(Pt));
    };

    float fr[8];
    unrollN<8>([&](auto U) { constexpr int u = U; fr[u] = fb[(2 + u) * TT + j]; });
    int k = 0;
    for (; k + 8 <= steps; k += 8) {
      float nf[8];
      unrollN<8>([&](auto U) {
        constexpr int u = U;
        int r = k + 10 + u; r = (r < SS) ? r : (SS - 1);
        nf[u] = fb[r * TT + j];
      });
      unrollN<8>([&](auto U) { constexpr int u = U; fwd_step(fr[u]); });
      unrollN<8>([&](auto U) { constexpr int u = U; fr[u] = nf[u]; });
    }
    unrollN<8>([&](auto U) {
      constexpr int u = U;
      if (k + u < steps) fwd_step(fr[u]);
    });

    // forward score: logsumexp over the 32 tags (each 32-group holds all tags)
    float m = p;
    unrollN<5>([&](auto D) { constexpr int d = 1 << D; m = fmaxf(m, bfly32<d>(m)); });
    float sacc = __expf(p - m);
    unrollN<5>([&](auto D) { constexpr int d = 1 << D; sacc += bfly32<d>(sacc); });
    if (tid == 0) ws_fwd[b] = m + __logf(sacc);

  } else if (blk < 2 * NB) {
    // ================= VITERBI (bit-exact vs reference) =================
    const int b = blk - NB;
    const int L = seq_length(mask, b, tid, mode);
    const int steps = L - 2;
    const float* fb = feats + (size_t)b * (SS * TT);
    unsigned char* bpb = ws_bp + (size_t)b * (KSTEPS * TT);

    float C[16];  // rows 16h..16h+15 of trans, column j
    unrollN<16>([&](auto I) {
      constexpr int ii = I;
      C[ii] = trans[(h * 16 + ii) * TT + j];
    });

    float p = fb[1 * TT + j];

    auto vit_step = [&](float fcur, int k) {
      float cur[16];
      unrollN<16>([&](auto I) {
        constexpr int ii = I;
        float d = fcur + C[ii];             // fl(f + trans)  (reference order)
        cur[ii] = bcast32<ii>(p) + d;       // fl(fl(f+trans) + part)
      });
      // exact max via tree (associative)
      float t8[8], t4[4];
      unrollN<8>([&](auto Q) { constexpr int q = Q; t8[q] = fmaxf(cur[2 * q], cur[2 * q + 1]); });
      unrollN<4>([&](auto Q) { constexpr int q = Q; t4[q] = fmaxf(t8[2 * q], t8[2 * q + 1]); });
      float vmax = fmaxf(fmaxf(t4[0], t4[1]), fmaxf(t4[2], t4[3]));
      // first-max index within this half (descending overwrite-on-equal, off critical path)
      int bi = 0;
      unrollN<16>([&](auto I) { constexpr int ii = 15 - I; bi = (cur[ii] == vmax) ? ii : bi; });
      int gi = bi | (h << 4);               // global source tag
      // cross-half combine (partner lane^48 owns same target tag, other i-range)
      float vo = __shfl_xor(vmax, 48, 64);
      int go = __shfl_xor(gi, 48, 64);
      bool take = (vo > vmax) || ((vo == vmax) && (go < gi));
      p = take ? vo : vmax;
      int bidx = take ? go : gi;
      if (tid < 32) bpb[k * TT + tid] = (unsigned char)bidx;  // lane l<32 owns tag l
    };

    float fr[8];
    unrollN<8>([&](auto U) { constexpr int u = U; fr[u] = fb[(2 + u) * TT + j]; });
    int k = 0;
    for (; k + 8 <= steps; k += 8) {
      float nf[8];
      unrollN<8>([&](auto U) {
        constexpr int u = U;
        int r = k + 10 + u; r = (r < SS) ? r : (SS - 1);
        nf[u] = fb[r * TT + j];
      });
      unrollN<8>([&](auto U) { constexpr int u = U; vit_step(fr[u], k + u); });
      unrollN<8>([&](auto U) { constexpr int u = U; fr[u] = nf[u]; });
    }
    unrollN<8>([&](auto U) {
      constexpr int u = U;
      if (k + u < steps) vit_step(fr[u], k + u);
    });

    // pointer = first-max argmax over tags of p
    float v = p;
    int idx = j;
    unrollN<5>([&](auto D) {
      constexpr int d = 1 << D;
      float vo = bfly32<d>(v);
      int io = bfly32i<d>(idx);
      bool take = (vo > v) || ((vo == v) && (io < idx));
      v = take ? vo : v;
      idx = take ? io : idx;
    });
    if (tid == 0) ws_ptr[b] = idx;
    // zero bp rows k in [steps, 510): reference masks bps to 0 there
    int* bpw = (int*)bpb;
    for (int w = steps * 8 + tid; w < KSTEPS * 8; w += 64) bpw[w] = 0;

  } else {
    // ================= GOLD SCORE =================
    const int b = blk - 2 * NB;
    float acc = 0.0f;
    for (int s = tid; s < SS; s += 64) {
      if (s == 0) continue;
      if (!mask_at(mask, b * SS + s, mode)) continue;
      int tg = tags[b * SS + s];
      if (tg == -100) tg = 0;
      float e = feats[((size_t)b * SS + s) * TT + tg];
      if (s >= 2) {
        int tp = tags[b * SS + s - 1];
        if (tp == -100) tp = 0;
        e += trans[tp * TT + tg];
      }
      acc += e;
    }
    for (int d = 1; d < 64; d <<= 1) acc += __shfl_xor(acc, d, 64);
    if (tid == 0) ws_gold[b] = acc;
  }
}

// ---------- K2: chunk-parallel backtrace + loss/path_score finish ----------
__global__ __launch_bounds__(512) void crf_backtrace_kernel(
    const unsigned char* __restrict__ ws_bp, const int* __restrict__ ws_ptr,
    const float* __restrict__ ws_fwd, const float* __restrict__ ws_gold,
    float* __restrict__ out) {
  __shared__ unsigned char bp[KSTEPS * TT];     // 16320 B
  __shared__ unsigned char path[KSTEPS * TT];   // 16320 B
  __shared__ int entries[8];

  const int b = blockIdx.x;
  const int tid = threadIdx.x;
  float* out_decode = out + 1 + NB;

  if (tid == 0) out[1 + b] = 0.0f;  // path_score = zeros(B)
  if (b == 0 && tid >= 64 && tid < 128) {
    // loss = (sum(fwd) - sum(gold)) / B   (one wave, independent of decode work)
    int t = tid - 64;
    float sf = 0.0f, sg = 0.0f;
    for (int r = 0; r < 4; ++r) { sf += ws_fwd[t + 64 * r]; sg += ws_gold[t + 64 * r]; }
    for (int d = 1; d < 64; d <<= 1) { sf += __shfl_xor(sf, d, 64); sg += __shfl_xor(sg, d, 64); }
    if (t == 0) out[0] = (sf - sg) / 256.0f;
  }

  // stage bp to LDS
  const int* src = (const int*)(ws_bp + (size_t)b * (KSTEPS * TT));
  int* dst = (int*)bp;
  for (int w = tid; w < KSTEPS * 8; w += 512) dst[w] = src[w];
  __syncthreads();

  // each wave = one 64-step chunk; lanes 0..31 = entry-tag hypotheses
  const int wave = tid >> 6;
  const int lane = tid & 63;
  if (lane < 32) {
    const int lo = wave * 64;
    const int hi = (lo + 64 < KSTEPS) ? (lo + 64) : KSTEPS;
    int ptr = lane;
    for (int k = hi - 1; k >= lo; --k) {
      ptr = bp[k * TT + ptr];
      path[k * TT + lane] = (unsigned char)ptr;
    }
  }
  __syncthreads();

  // compose chunk entries from the top (chunk 7 enters with pointer)
  if (tid == 0) {
    int e = ws_ptr[b];
    for (int c = 7; c >= 0; --c) {
      entries[c] = e;
      e = path[(c * 64) * TT + e];
    }
  }
  __syncthreads();

  // decode row: [0, ptrs[0..509], pointer]
  const int s = tid;
  int val;
  if (s == 0) val = 0;
  else if (s <= KSTEPS) { int k = s - 1; val = path[k * TT + entries[k >> 6]]; }
  else val = ws_ptr[b];
  out_decode[(size_t)b * SS + s] = (float)val;
}

extern "C" void kernel_launch(void* const* d_in, const int* in_sizes, int n_in,
                              void* d_out, int out_size, void* d_ws, size_t ws_size,
                              hipStream_t stream) {
  const float* feats = (const float*)d_in[0];
  const float* trans = (const float*)d_in[1];
  const void* mask = d_in[2];
  const int* tags = (const int*)d_in[3];
  float* out = (float*)d_out;

  unsigned char* ws = (unsigned char*)d_ws;
  const size_t BP_BYTES = (size_t)NB * KSTEPS * TT;  // 4,177,920
  unsigned char* ws_bp = ws;
  float* ws_fwd = (float*)(ws + BP_BYTES);
  float* ws_gold = (float*)(ws + BP_BYTES + 1024);
  int* ws_ptr = (int*)(ws + BP_BYTES + 2048);

  hipLaunchKernelGGL(crf_main_kernel, dim3(3 * NB), dim3(64), 0, stream,
                     feats, trans, mask, tags, ws_bp, ws_fwd, ws_gold, ws_ptr);
  hipLaunchKernelGGL(crf_backtrace_kernel, dim3(NB), dim3(512), 0, stream,
                     ws_bp, ws_ptr, ws_fwd, ws_gold, out);
}

// Round 4
// 169.858 us; speedup vs baseline: 2.1791x; 1.0546x over previous
//
#include <hip/hip_runtime.h>
#include <cstdint>
#include <cstddef>
#include <utility>

#define SS 512
#define TT 32
#define NB 256
#define KSTEPS 510  // SS-2

// ---------- unroll helper (compile-time indices -> registers, swizzle imms) ----------
template <typename F, size_t... Is>
__device__ __forceinline__ void unroll_impl(F&& f, std::index_sequence<Is...>) {
  (f(std::integral_constant<int, (int)Is>{}), ...);
}
template <int N, typename F>
__device__ __forceinline__ void unrollN(F&& f) {
  unroll_impl(f, std::make_index_sequence<N>{});
}

// broadcast lane I within each 32-lane group (BitMode: and=0, or=I, xor=0)
template <int I>
__device__ __forceinline__ float bcast32(float v) {
  return __int_as_float(__builtin_amdgcn_ds_swizzle(__float_as_int(v), (I << 5)));
}
// butterfly xor D within each 32-lane group (and=0x1f, xor=D)
template <int D>
__device__ __forceinline__ float bfly32(float v) {
  return __int_as_float(__builtin_amdgcn_ds_swizzle(__float_as_int(v), (D << 10) | 0x1f));
}
template <int D>
__device__ __forceinline__ int bfly32i(int v) {
  return __builtin_amdgcn_ds_swizzle(v, (D << 10) | 0x1f);
}
// value from lane (l ^ 48); addr precomputed = (l^48)<<2
__device__ __forceinline__ float bperm(int addr, float v) {
  return __int_as_float(__builtin_amdgcn_ds_bpermute(addr, __float_as_int(v)));
}

// ---------- mask dtype autodetect (bool may arrive as i32 / u8 / f32) ----------
__device__ __forceinline__ int mask_mode(const void* m) {
  int w0 = ((const int*)m)[0];          // element (0,0) is always true (L>=256)
  if (w0 == 1) return 0;                // int32 0/1
  if (w0 == 0x3f800000) return 2;       // float32 1.0
  return 1;                             // uint8
}
__device__ __forceinline__ bool mask_at(const void* m, int idx, int mode) {
  if (mode == 0) return ((const int*)m)[idx] != 0;
  if (mode == 2) return ((const float*)m)[idx] != 0.0f;
  return ((const unsigned char*)m)[idx] != 0;
}

__device__ __forceinline__ int seq_length(const void* mask, int b, int tid, int mode) {
  int cnt = 0;
  for (int s = tid; s < SS; s += 64) cnt += mask_at(mask, b * SS + s, mode) ? 1 : 0;
  for (int d = 1; d < 64; d <<= 1) cnt += __shfl_xor(cnt, d, 64);
  return cnt;
}

// ---------- K1: fused forward / viterbi / gold (role by blockIdx) ----------
// Lane layout: lane l owns tag j = (l&31) ^ ((l>>5)<<4). Group g = l>>5 covers
// source tags i in [16g, 16g+16): bcast32<ii> delivers p[16g+ii] to group g.
// Cross-half combine via ds_bpermute from lane l^48 (partner owning same tag).
__global__ __launch_bounds__(64) void crf_main_kernel(
    const float* __restrict__ feats, const float* __restrict__ trans,
    const void* __restrict__ mask, const int* __restrict__ tags,
    unsigned char* __restrict__ ws_bp, float* __restrict__ ws_fwd,
    float* __restrict__ ws_gold, int* __restrict__ ws_ptr) {
  const int blk = blockIdx.x;
  const int tid = threadIdx.x;
  const int mode = mask_mode(mask);

  const int h = tid >> 5;                       // half / group
  const int j = (tid & 31) ^ (h << 4);          // owned tag (permuted in half 1)
  const int xaddr = (tid ^ 48) << 2;            // bpermute addr for same-tag partner

  if (blk < NB) {
    // ========== FORWARD, exp-space: q' = exp(f) * (E^T q), exact 2^k rescale ==========
    const int b = blk;
    const int L = seq_length(mask, b, tid, mode);
    const int steps = L - 2;
    const float* fb = feats + (size_t)b * (SS * TT);

    float E[16];  // rows 16h..16h+15 of exp(trans), column j
    unrollN<16>([&](auto I) {
      constexpr int ii = I;
      E[ii] = __expf(trans[(h * 16 + ii) * TT + j]);
    });

    float q = __expf(fb[1 * TT + j]);
    int Eacc = 0;

    auto rescale = [&]() {
      int qb = __builtin_amdgcn_readfirstlane(__float_as_int(q));
      int e = (qb >> 23) & 0xff;
      Eacc += e - 127;
      q *= __int_as_float((254 - e) << 23);   // exact power-of-two scale
    };

    auto fwd_step = [&](float ef) {
      float bc[16];
      unrollN<16>([&](auto I) { constexpr int ii = I; bc[ii] = bcast32<ii>(q); });
      __builtin_amdgcn_sched_barrier(0);       // all 16 swizzles issue before consumers
      float P0 = 0.f, P1 = 0.f, P2 = 0.f, P3 = 0.f;
      unrollN<16>([&](auto I) {
        constexpr int ii = I;
        if constexpr ((ii & 3) == 0) P0 = fmaf(bc[ii], E[ii], P0);
        else if constexpr ((ii & 3) == 1) P1 = fmaf(bc[ii], E[ii], P1);
        else if constexpr ((ii & 3) == 2) P2 = fmaf(bc[ii], E[ii], P2);
        else P3 = fmaf(bc[ii], E[ii], P3);
      });
      float P = (P0 + P1) + (P2 + P3);
      float Pt = P + bperm(xaddr, P);          // add partner half's partial
      q = ef * Pt;
    };

    float EF[8];
    unrollN<8>([&](auto U) { constexpr int u = U; EF[u] = __expf(fb[(2 + u) * TT + j]); });
    int k = 0;
    for (; k + 8 <= steps; k += 8) {
      float nf[8];
      unrollN<8>([&](auto U) {
        constexpr int u = U;
        int r = k + 10 + u; r = (r < SS) ? r : (SS - 1);
        nf[u] = fb[r * TT + j];
      });
      unrollN<8>([&](auto U) {
        constexpr int u = U;
        if constexpr ((u & 3) == 0) rescale();
        fwd_step(EF[u]);
      });
      unrollN<8>([&](auto U) { constexpr int u = U; EF[u] = __expf(nf[u]); });
    }
    unrollN<8>([&](auto U) {
      constexpr int u = U;
      if (k + u < steps) {
        if constexpr ((u & 3) == 0) rescale();
        fwd_step(EF[u]);
      }
    });

    // forward score = log(sum_j q_j) + Eacc*ln2 (each 32-group holds all tags)
    float s = q;
    unrollN<5>([&](auto D) { constexpr int d = 1 << D; s += bfly32<d>(s); });
    if (tid == 0) ws_fwd[b] = __logf(s) + (float)Eacc * 0.69314718056f;

  } else if (blk < 2 * NB) {
    // ================= VITERBI (bit-exact vs reference) =================
    const int b = blk - NB;
    const int L = seq_length(mask, b, tid, mode);
    const int steps = L - 2;
    const float* fb = feats + (size_t)b * (SS * TT);
    unsigned char* bpb = ws_bp + (size_t)b * (KSTEPS * TT);

    float C[16];  // rows 16h..16h+15 of trans, column j
    unrollN<16>([&](auto I) {
      constexpr int ii = I;
      C[ii] = trans[(h * 16 + ii) * TT + j];
    });

    float p = fb[1 * TT + j];

    auto vit_step = [&](float fcur, int k) {
      float bc[16];
      unrollN<16>([&](auto I) { constexpr int ii = I; bc[ii] = bcast32<ii>(p); });
      __builtin_amdgcn_sched_barrier(0);       // batch swizzle issue
      float dd[16], cur[16];
      unrollN<16>([&](auto I) { constexpr int ii = I; dd[ii] = fcur + C[ii]; });  // fl(f+trans)
      unrollN<16>([&](auto I) { constexpr int ii = I; cur[ii] = bc[ii] + dd[ii]; });
      // exact max via max3-friendly tree (max is associative/exact)
      float t[5];
      unrollN<5>([&](auto Q) {
        constexpr int q5 = Q;
        t[q5] = fmaxf(fmaxf(cur[3 * q5], cur[3 * q5 + 1]), cur[3 * q5 + 2]);
      });
      float vmax = fmaxf(fmaxf(fmaxf(t[0], t[1]), t[2]),
                         fmaxf(fmaxf(t[3], t[4]), cur[15]));
      float sw = bperm(xaddr, vmax);           // partner half's partial max (issue early)
      __builtin_amdgcn_sched_barrier(0);
      // first-max index within this half (descending overwrite-on-equal, off DS path)
      int bi = 0;
      unrollN<16>([&](auto I) { constexpr int ii = 15 - I; bi = (cur[ii] == vmax) ? ii : bi; });
      // combine: on tie the half-0 index (smaller global) must win -> half0 keeps
      bool myWin = (vmax > sw) || ((vmax == sw) && (h == 0));
      p = myWin ? vmax : sw;
      if (myWin) bpb[k * TT + j] = (unsigned char)(bi | (h << 4));  // winner stores own idx
    };

    float fr[8];
    unrollN<8>([&](auto U) { constexpr int u = U; fr[u] = fb[(2 + u) * TT + j]; });
    int k = 0;
    for (; k + 8 <= steps; k += 8) {
      float nf[8];
      unrollN<8>([&](auto U) {
        constexpr int u = U;
        int r = k + 10 + u; r = (r < SS) ? r : (SS - 1);
        nf[u] = fb[r * TT + j];
      });
      unrollN<8>([&](auto U) { constexpr int u = U; vit_step(fr[u], k + u); });
      unrollN<8>([&](auto U) { constexpr int u = U; fr[u] = nf[u]; });
    }
    unrollN<8>([&](auto U) {
      constexpr int u = U;
      if (k + u < steps) vit_step(fr[u], k + u);
    });

    // pointer = first-max argmax over tags of p (any 32-group holds all tags)
    float v = p;
    int idx = j;
    unrollN<5>([&](auto D) {
      constexpr int d = 1 << D;
      float vo = bfly32<d>(v);
      int io = bfly32i<d>(idx);
      bool take = (vo > v) || ((vo == v) && (io < idx));
      v = take ? vo : v;
      idx = take ? io : idx;
    });
    if (tid == 0) ws_ptr[b] = idx;
    // zero bp rows k in [steps, 510): reference masks bps to 0 there
    int* bpw = (int*)bpb;
    for (int w = steps * 8 + tid; w < KSTEPS * 8; w += 64) bpw[w] = 0;

  } else {
    // ================= GOLD SCORE =================
    const int b = blk - 2 * NB;
    float acc = 0.0f;
    for (int s = tid; s < SS; s += 64) {
      if (s == 0) continue;
      if (!mask_at(mask, b * SS + s, mode)) continue;
      int tg = tags[b * SS + s];
      if (tg == -100) tg = 0;
      float e = feats[((size_t)b * SS + s) * TT + tg];
      if (s >= 2) {
        int tp = tags[b * SS + s - 1];
        if (tp == -100) tp = 0;
        e += trans[tp * TT + tg];
      }
      acc += e;
    }
    for (int d = 1; d < 64; d <<= 1) acc += __shfl_xor(acc, d, 64);
    if (tid == 0) ws_gold[b] = acc;
  }
}

// ---------- K2: chunk-parallel backtrace + loss/path_score finish ----------
__global__ __launch_bounds__(512) void crf_backtrace_kernel(
    const unsigned char* __restrict__ ws_bp, const int* __restrict__ ws_ptr,
    const float* __restrict__ ws_fwd, const float* __restrict__ ws_gold,
    float* __restrict__ out) {
  __shared__ unsigned char bp[KSTEPS * TT];     // 16320 B
  __shared__ unsigned char path[KSTEPS * TT];   // 16320 B
  __shared__ int entries[8];

  const int b = blockIdx.x;
  const int tid = threadIdx.x;
  float* out_decode = out + 1 + NB;

  if (tid == 0) out[1 + b] = 0.0f;  // path_score = zeros(B)
  if (b == 0 && tid >= 64 && tid < 128) {
    int t = tid - 64;
    float sf = 0.0f, sg = 0.0f;
    for (int r = 0; r < 4; ++r) { sf += ws_fwd[t + 64 * r]; sg += ws_gold[t + 64 * r]; }
    for (int d = 1; d < 64; d <<= 1) { sf += __shfl_xor(sf, d, 64); sg += __shfl_xor(sg, d, 64); }
    if (t == 0) out[0] = (sf - sg) / 256.0f;
  }

  // stage bp to LDS
  const int* src = (const int*)(ws_bp + (size_t)b * (KSTEPS * TT));
  int* dst = (int*)bp;
  for (int w = tid; w < KSTEPS * 8; w += 512) dst[w] = src[w];
  __syncthreads();

  // each wave = one 64-step chunk; lanes 0..31 = entry-tag hypotheses
  const int wave = tid >> 6;
  const int lane = tid & 63;
  if (lane < 32) {
    const int lo = wave * 64;
    const int hi = (lo + 64 < KSTEPS) ? (lo + 64) : KSTEPS;
    int ptr = lane;
    for (int k = hi - 1; k >= lo; --k) {
      ptr = bp[k * TT + ptr];
      path[k * TT + lane] = (unsigned char)ptr;
    }
  }
  __syncthreads();

  // compose chunk entries from the top (chunk 7 enters with pointer)
  if (tid == 0) {
    int e = ws_ptr[b];
    for (int c = 7; c >= 0; --c) {
      entries[c] = e;
      e = path[(c * 64) * TT + e];
    }
  }
  __syncthreads();

  // decode row: [0, ptrs[0..509], pointer]
  const int s = tid;
  int val;
  if (s == 0) val = 0;
  else if (s <= KSTEPS) { int k = s - 1; val = path[k * TT + entries[k >> 6]]; }
  else val = ws_ptr[b];
  out_decode[(size_t)b * SS + s] = (float)val;
}

extern "C" void kernel_launch(void* const* d_in, const int* in_sizes, int n_in,
                              void* d_out, int out_size, void* d_ws, size_t ws_size,
                              hipStream_t stream) {
  const float* feats = (const float*)d_in[0];
  const float* trans = (const float*)d_in[1];
  const void* mask = d_in[2];
  const int* tags = (const int*)d_in[3];
  float* out = (float*)d_out;

  unsigned char* ws = (unsigned char*)d_ws;
  const size_t BP_BYTES = (size_t)NB * KSTEPS * TT;  // 4,177,920
  unsigned char* ws_bp = ws;
  float* ws_fwd = (float*)(ws + BP_BYTES);
  float* ws_gold = (float*)(ws + BP_BYTES + 1024);
  int* ws_ptr = (int*)(ws + BP_BYTES + 2048);

  hipLaunchKernelGGL(crf_main_kernel, dim3(3 * NB), dim3(64), 0, stream,
                     feats, trans, mask, tags, ws_bp, ws_fwd, ws_gold, ws_ptr);
  hipLaunchKernelGGL(crf_backtrace_kernel, dim3(NB), dim3(512), 0, stream,
                     ws_bp, ws_ptr, ws_fwd, ws_gold, out);
}

// Round 6
// 156.925 us; speedup vs baseline: 2.3587x; 1.0824x over previous
//
#include <hip/hip_runtime.h>
#include <cstdint>
#include <cstddef>
#include <utility>

#define SS 512
#define TT 32
#define NB 256
#define KSTEPS 510  // SS-2

// ---------- unroll helper (compile-time indices -> registers) ----------
template <typename F, size_t... Is>
__device__ __forceinline__ void unroll_impl(F&& f, std::index_sequence<Is...>) {
  (f(std::integral_constant<int, (int)Is>{}), ...);
}
template <int N, typename F>
__device__ __forceinline__ void unrollN(F&& f) {
  unroll_impl(f, std::make_index_sequence<N>{});
}

// butterfly xor D within each 32-lane group (one-time reductions only)
template <int D>
__device__ __forceinline__ float bfly32(float v) {
  return __int_as_float(__builtin_amdgcn_ds_swizzle(__float_as_int(v), (D << 10) | 0x1f));
}
template <int D>
__device__ __forceinline__ int bfly32i(int v) {
  return __builtin_amdgcn_ds_swizzle(v, (D << 10) | 0x1f);
}

// ---------- mask dtype autodetect (bool may arrive as i32 / u8 / f32) ----------
__device__ __forceinline__ int mask_mode(const void* m) {
  int w0 = ((const int*)m)[0];          // element (0,0) is always true (L>=256)
  if (w0 == 1) return 0;                // int32 0/1
  if (w0 == 0x3f800000) return 2;       // float32 1.0
  return 1;                             // uint8
}
__device__ __forceinline__ bool mask_at(const void* m, int idx, int mode) {
  if (mode == 0) return ((const int*)m)[idx] != 0;
  if (mode == 2) return ((const float*)m)[idx] != 0.0f;
  return ((const unsigned char*)m)[idx] != 0;
}

__device__ __forceinline__ int seq_length(const void* mask, int b, int tid, int mode) {
  int cnt = 0;
  for (int s = tid; s < SS; s += 64) cnt += mask_at(mask, b * SS + s, mode) ? 1 : 0;
  for (int d = 1; d < 64; d <<= 1) cnt += __shfl_xor(cnt, d, 64);
  return cnt;
}

// ---------- K1: fused forward / viterbi / gold (role by blockIdx) ----------
// Lane l owns tag j = l&31 (lanes l and l+32 duplicate tag j). Half h = l>>5
// reduces source tags i in [16h, 16h+16). Transport: partition lives in a
// 32-float LDS array; per step: 1 ds_write_b32 (both halves, same addr+value)
// + 4 uniform-address ds_read_b128 broadcasts. Cross-half combine: one
// __shfl_xor(...,32) (ds_bpermute, proven in rounds 2-4).
__global__ __launch_bounds__(64) void crf_main_kernel(
    const float* __restrict__ feats, const float* __restrict__ trans,
    const void* __restrict__ mask, const int* __restrict__ tags,
    unsigned char* __restrict__ ws_bp, float* __restrict__ ws_fwd,
    float* __restrict__ ws_gold, int* __restrict__ ws_ptr) {
  const int blk = blockIdx.x;
  const int tid = threadIdx.x;
  const int mode = mask_mode(mask);
  const int h = tid >> 5;   // source half
  const int j = tid & 31;   // owned tag

  __shared__ __align__(16) float qlds[TT];

  if (blk < NB) {
    // ========== FORWARD, exp-space: q' = exp(f) * (E^T q), exact 2^k rescale ==========
    const int b = blk;
    const int L = seq_length(mask, b, tid, mode);
    const int steps = L - 2;
    const float* fb = feats + (size_t)b * (SS * TT);

    float E[16];  // rows 16h..16h+15 of exp(trans), column j
    unrollN<16>([&](auto I) {
      constexpr int ii = I;
      E[ii] = __expf(trans[(h * 16 + ii) * TT + j]);
    });

    float q = __expf(fb[TT + j]);
    int Eacc = 0;
    qlds[j] = q;
    asm volatile("" ::: "memory");
    const float4* qvh = (const float4*)qlds + h * 4;

    float fA = fb[2 * TT + j], fB = fb[3 * TT + j], fC = fb[4 * TT + j];

    auto step = [&](int k, bool resc) {
      int r5 = k + 5; r5 = (r5 < SS) ? r5 : (SS - 1);
      float fD = fb[r5 * TT + j];                       // prefetch depth-3
      float4 R0 = qvh[0], R1 = qvh[1], R2 = qvh[2], R3 = qvh[3];
      float ef = __expf(fA);
      float P0 = fmaf(R0.x, E[0], fmaf(R1.x, E[4], fmaf(R2.x, E[8],  R3.x * E[12])));
      float P1 = fmaf(R0.y, E[1], fmaf(R1.y, E[5], fmaf(R2.y, E[9],  R3.y * E[13])));
      float P2 = fmaf(R0.z, E[2], fmaf(R1.z, E[6], fmaf(R2.z, E[10], R3.z * E[14])));
      float P3 = fmaf(R0.w, E[3], fmaf(R1.w, E[7], fmaf(R2.w, E[11], R3.w * E[15])));
      float P = (P0 + P1) + (P2 + P3);
      float Pt = P + __shfl_xor(P, 32, 64);             // combine halves (bitwise same both halves)
      q = ef * Pt;
      if (resc) {
        int qb = __builtin_amdgcn_readfirstlane(__float_as_int(q));
        int e = (qb >> 23) & 0xff;
        Eacc += e - 127;
        q *= __int_as_float((254 - e) << 23);           // exact power-of-two scale
      }
      qlds[j] = q;
      asm volatile("" ::: "memory");
      fA = fB; fB = fC; fC = fD;
    };

    int k = 0;
    for (; k + 4 <= steps; k += 4) {
      step(k, false); step(k + 1, false); step(k + 2, false); step(k + 3, true);
    }
    for (; k < steps; ++k) step(k, false);

    // forward score = log(sum_j q_j) + Eacc*ln2
    float s = q;
    unrollN<5>([&](auto D) { constexpr int d = 1 << D; s += bfly32<d>(s); });
    if (tid == 0) ws_fwd[b] = __logf(s) + (float)Eacc * 0.69314718056f;

  } else if (blk < 2 * NB) {
    // ================= VITERBI (bit-exact vs reference) =================
    const int b = blk - NB;
    const int L = seq_length(mask, b, tid, mode);
    const int steps = L - 2;
    const float* fb = feats + (size_t)b * (SS * TT);
    unsigned char* bpb = ws_bp + (size_t)b * (KSTEPS * TT);

    float C[16];  // rows 16h..16h+15 of trans, column j
    unrollN<16>([&](auto I) {
      constexpr int ii = I;
      C[ii] = trans[(h * 16 + ii) * TT + j];
    });

    float p = fb[TT + j];
    qlds[j] = p;
    asm volatile("" ::: "memory");
    const float4* qvh = (const float4*)qlds + h * 4;

    float fA = fb[2 * TT + j], fB = fb[3 * TT + j], fC = fb[4 * TT + j];

    auto step = [&](int k) {
      int r5 = k + 5; r5 = (r5 < SS) ? r5 : (SS - 1);
      float fD = fb[r5 * TT + j];
      float4 R0 = qvh[0], R1 = qvh[1], R2 = qvh[2], R3 = qvh[3];
      float dd[16];
      unrollN<16>([&](auto I) { constexpr int ii = I; dd[ii] = fA + C[ii]; });  // fl(f+trans)
      float cur[16];
      cur[0] = R0.x + dd[0];  cur[1] = R0.y + dd[1];  cur[2] = R0.z + dd[2];  cur[3] = R0.w + dd[3];
      cur[4] = R1.x + dd[4];  cur[5] = R1.y + dd[5];  cur[6] = R1.z + dd[6];  cur[7] = R1.w + dd[7];
      cur[8] = R2.x + dd[8];  cur[9] = R2.y + dd[9];  cur[10] = R2.z + dd[10]; cur[11] = R2.w + dd[11];
      cur[12] = R3.x + dd[12]; cur[13] = R3.y + dd[13]; cur[14] = R3.z + dd[14]; cur[15] = R3.w + dd[15];
      // exact max tree (max3-fusable; fmax exact regardless of grouping)
      float t0 = fmaxf(fmaxf(cur[0], cur[1]), cur[2]);
      float t1 = fmaxf(fmaxf(cur[3], cur[4]), cur[5]);
      float t2 = fmaxf(fmaxf(cur[6], cur[7]), cur[8]);
      float t3 = fmaxf(fmaxf(cur[9], cur[10]), cur[11]);
      float t4 = fmaxf(fmaxf(cur[12], cur[13]), cur[14]);
      float vmax = fmaxf(fmaxf(fmaxf(t0, t1), t2), fmaxf(fmaxf(t3, t4), cur[15]));
      // cross-half partial-max exchange (issue early; DS latency overlaps scan)
      float vo = __shfl_xor(vmax, 32, 64);
      // first-max index within this half (descending overwrite-on-equal)
      int bi = 15;
      unrollN<16>([&](auto I) { constexpr int ii = 15 - I; bi = (cur[ii] == vmax) ? ii : bi; });
      // winner resolution: tie -> half0 (smaller global source index, = jnp.argmax)
      bool win = (vmax > vo) || ((vmax == vo) && (h == 0));
      float pw = win ? vmax : vo;                        // same value in both halves
      if (win) bpb[k * TT + j] = (unsigned char)((h << 4) | bi);  // exactly one store per tag
      p = pw;
      qlds[j] = pw;
      asm volatile("" ::: "memory");
      fA = fB; fB = fC; fC = fD;
    };

    int k = 0;
    for (; k + 4 <= steps; k += 4) { step(k); step(k + 1); step(k + 2); step(k + 3); }
    for (; k < steps; ++k) step(k);

    // pointer = first-max argmax over tags of p
    float v = p;
    int idx = j;
    unrollN<5>([&](auto D) {
      constexpr int d = 1 << D;
      float vo = bfly32<d>(v);
      int io = bfly32i<d>(idx);
      bool take = (vo > v) || ((vo == v) && (io < idx));
      v = take ? vo : v;
      idx = take ? io : idx;
    });
    if (tid == 0) ws_ptr[b] = idx;
    // zero bp rows k in [steps, 510): reference masks bps to 0 there
    int* bpw = (int*)bpb;
    for (int w = steps * 8 + tid; w < KSTEPS * 8; w += 64) bpw[w] = 0;

  } else {
    // ================= GOLD SCORE =================
    const int b = blk - 2 * NB;
    float acc = 0.0f;
    for (int s = tid; s < SS; s += 64) {
      if (s == 0) continue;
      if (!mask_at(mask, b * SS + s, mode)) continue;
      int tg = tags[b * SS + s];
      if (tg == -100) tg = 0;
      float e = feats[((size_t)b * SS + s) * TT + tg];
      if (s >= 2) {
        int tp = tags[b * SS + s - 1];
        if (tp == -100) tp = 0;
        e += trans[tp * TT + tg];
      }
      acc += e;
    }
    for (int d = 1; d < 64; d <<= 1) acc += __shfl_xor(acc, d, 64);
    if (tid == 0) ws_gold[b] = acc;
  }
}

// ---------- K2: chunk-parallel backtrace + loss/path_score finish ----------
__global__ __launch_bounds__(512) void crf_backtrace_kernel(
    const unsigned char* __restrict__ ws_bp, const int* __restrict__ ws_ptr,
    const float* __restrict__ ws_fwd, const float* __restrict__ ws_gold,
    float* __restrict__ out) {
  __shared__ unsigned char bp[KSTEPS * TT];     // 16320 B
  __shared__ unsigned char path[KSTEPS * TT];   // 16320 B
  __shared__ int entries[8];

  const int b = blockIdx.x;
  const int tid = threadIdx.x;
  float* out_decode = out + 1 + NB;

  if (tid == 0) out[1 + b] = 0.0f;  // path_score = zeros(B)
  if (b == 0 && tid >= 64 && tid < 128) {
    int t = tid - 64;
    float sf = 0.0f, sg = 0.0f;
    for (int r = 0; r < 4; ++r) { sf += ws_fwd[t + 64 * r]; sg += ws_gold[t + 64 * r]; }
    for (int d = 1; d < 64; d <<= 1) { sf += __shfl_xor(sf, d, 64); sg += __shfl_xor(sg, d, 64); }
    if (t == 0) out[0] = (sf - sg) / 256.0f;
  }

  // stage bp to LDS
  const int* src = (const int*)(ws_bp + (size_t)b * (KSTEPS * TT));
  int* dst = (int*)bp;
  for (int w = tid; w < KSTEPS * 8; w += 512) dst[w] = src[w];
  __syncthreads();

  // each wave = one 64-step chunk; lanes 0..31 = entry-tag hypotheses
  const int wave = tid >> 6;
  const int lane = tid & 63;
  if (lane < 32) {
    const int lo = wave * 64;
    const int hi = (lo + 64 < KSTEPS) ? (lo + 64) : KSTEPS;
    int ptr = lane;
    for (int k = hi - 1; k >= lo; --k) {
      ptr = bp[k * TT + ptr];
      path[k * TT + lane] = (unsigned char)ptr;
    }
  }
  __syncthreads();

  // compose chunk entries from the top (chunk 7 enters with pointer)
  if (tid == 0) {
    int e = ws_ptr[b];
    for (int c = 7; c >= 0; --c) {
      entries[c] = e;
      e = path[(c * 64) * TT + e];
    }
  }
  __syncthreads();

  // decode row: [0, ptrs[0..509], pointer]
  const int s = tid;
  int val;
  if (s == 0) val = 0;
  else if (s <= KSTEPS) { int k = s - 1; val = path[k * TT + entries[k >> 6]]; }
  else val = ws_ptr[b];
  out_decode[(size_t)b * SS + s] = (float)val;
}

extern "C" void kernel_launch(void* const* d_in, const int* in_sizes, int n_in,
                              void* d_out, int out_size, void* d_ws, size_t ws_size,
                              hipStream_t stream) {
  const float* feats = (const float*)d_in[0];
  const float* trans = (const float*)d_in[1];
  const void* mask = d_in[2];
  const int* tags = (const int*)d_in[3];
  float* out = (float*)d_out;

  unsigned char* ws = (unsigned char*)d_ws;
  const size_t BP_BYTES = (size_t)NB * KSTEPS * TT;  // 4,177,920
  unsigned char* ws_bp = ws;
  float* ws_fwd = (float*)(ws + BP_BYTES);
  float* ws_gold = (float*)(ws + BP_BYTES + 1024);
  int* ws_ptr = (int*)(ws + BP_BYTES + 2048);

  hipLaunchKernelGGL(crf_main_kernel, dim3(3 * NB), dim3(64), 0, stream,
                     feats, trans, mask, tags, ws_bp, ws_fwd, ws_gold, ws_ptr);
  hipLaunchKernelGGL(crf_backtrace_kernel, dim3(NB), dim3(512), 0, stream,
                     ws_bp, ws_ptr, ws_fwd, ws_gold, out);
}